// Round 1
// baseline (1123.478 us; speedup 1.0000x reference)
//
#include <hip/hip_runtime.h>
#include <hip/hip_bf16.h>

// PointTransformerConv-style block, fp32 correctness-first version.
// Pass A: node projections (x1 -> v, a_src, a_dst)
// Pass B: per-edge pos-MLP + attn-MLP, exp, atomic accumulate num/den per dst
//         (segment-max skipped: alpha = relu(..) >= 0, softmax is shift-invariant)
// Pass C: per-node normalize + output GEMM + relu

#define WAVES_PER_BLOCK 4

__global__ __launch_bounds__(256) void node_in_kernel(
    const float* __restrict__ x, const float* __restrict__ W_in, const float* __restrict__ b_in,
    const float* __restrict__ W_lin, const float* __restrict__ W_src, const float* __restrict__ W_dst,
    float* __restrict__ v, float* __restrict__ a_src, float* __restrict__ a_dst, int N) {
  __shared__ float sW[3 * 4096];          // W_in, W_lin, W_src (W_dst from global/L2)
  __shared__ float sb[64];
  __shared__ float xbuf[WAVES_PER_BLOCK][64];
  __shared__ float x1buf[WAVES_PER_BLOCK][64];
  for (int i = threadIdx.x; i < 4096; i += 256) {
    sW[i] = W_in[i]; sW[4096 + i] = W_lin[i]; sW[8192 + i] = W_src[i];
  }
  if (threadIdx.x < 64) sb[threadIdx.x] = b_in[threadIdx.x];
  __syncthreads();
  const int w = threadIdx.x >> 6, c = threadIdx.x & 63;
  const int npi = gridDim.x * WAVES_PER_BLOCK;
  const int iters = (N + npi - 1) / npi;
  for (int it = 0; it < iters; ++it) {
    const int n = it * npi + blockIdx.x * WAVES_PER_BLOCK + w;
    const bool act = n < N;
    xbuf[w][c] = act ? x[n * 64 + c] : 0.f;
    __syncthreads();
    float acc = sb[c];
#pragma unroll
    for (int k = 0; k < 64; ++k) acc += xbuf[w][k] * sW[k * 64 + c];
    x1buf[w][c] = fmaxf(acc, 0.f);
    __syncthreads();
    float av = 0.f, as = 0.f, ad = 0.f;
#pragma unroll
    for (int k = 0; k < 64; ++k) {
      const float xv = x1buf[w][k];
      av += xv * sW[4096 + k * 64 + c];
      as += xv * sW[8192 + k * 64 + c];
      ad += xv * W_dst[k * 64 + c];   // L1/L2-resident (16KB)
    }
    if (act) { v[n * 64 + c] = av; a_src[n * 64 + c] = as; a_dst[n * 64 + c] = ad; }
    __syncthreads();
  }
}

__global__ __launch_bounds__(256) void edge_kernel(
    const float* __restrict__ pos,
    const float* __restrict__ v, const float* __restrict__ a_src, const float* __restrict__ a_dst,
    const float* __restrict__ pW1, const float* __restrict__ pb1,
    const float* __restrict__ pW2, const float* __restrict__ pb2,
    const float* __restrict__ aW1, const float* __restrict__ ab1,
    const float* __restrict__ aW2, const float* __restrict__ ab2,
    const int* __restrict__ eidx,
    float* __restrict__ num, float* __restrict__ den, int E) {
  __shared__ float sW[3 * 4096];          // pos_W2, att_W1, att_W2
  __shared__ float sPW1[3 * 64];
  __shared__ float sB[4 * 64];            // pb1, pb2, ab1, ab2
  __shared__ float tbuf[WAVES_PER_BLOCK][64];
  for (int i = threadIdx.x; i < 4096; i += 256) {
    sW[i] = pW2[i]; sW[4096 + i] = aW1[i]; sW[8192 + i] = aW2[i];
  }
  if (threadIdx.x < 192) sPW1[threadIdx.x] = pW1[threadIdx.x];
  if (threadIdx.x < 64) {
    sB[threadIdx.x] = pb1[threadIdx.x];
    sB[64 + threadIdx.x] = pb2[threadIdx.x];
    sB[128 + threadIdx.x] = ab1[threadIdx.x];
    sB[192 + threadIdx.x] = ab2[threadIdx.x];
  }
  __syncthreads();

  const int w = threadIdx.x >> 6, c = threadIdx.x & 63;
  const int epi = gridDim.x * WAVES_PER_BLOCK;
  const int iters = (E + epi - 1) / epi;
  for (int it = 0; it < iters; ++it) {
    const int e = it * epi + blockIdx.x * WAVES_PER_BLOCK + w;
    const bool act = e < E;
    int src = 0, dst = 0;
    float d0 = 0.f, d1 = 0.f, d2 = 0.f;
    if (act) {
      src = eidx[e];
      dst = eidx[E + e];
      d0 = pos[dst * 3 + 0] - pos[src * 3 + 0];
      d1 = pos[dst * 3 + 1] - pos[src * 3 + 1];
      d2 = pos[dst * 3 + 2] - pos[src * 3 + 2];
    }
    // pos MLP layer 1 (3 -> 64)
    const float h = fmaxf(sB[c] + d0 * sPW1[c] + d1 * sPW1[64 + c] + d2 * sPW1[128 + c], 0.f);
    tbuf[w][c] = h;
    __syncthreads();
    // pos MLP layer 2 (64 -> 64)
    float acc = sB[64 + c];
#pragma unroll
    for (int k = 0; k < 64; ++k) acc += tbuf[w][k] * sW[k * 64 + c];
    const float delta = fmaxf(acc, 0.f);
    __syncthreads();
    // t = a_dst[dst] - a_src[src] + delta
    float t = delta;
    if (act) t += a_dst[dst * 64 + c] - a_src[src * 64 + c];
    tbuf[w][c] = t;
    __syncthreads();
    // attn MLP layer 1
    acc = sB[128 + c];
#pragma unroll
    for (int k = 0; k < 64; ++k) acc += tbuf[w][k] * sW[4096 + k * 64 + c];
    const float g = fmaxf(acc, 0.f);
    __syncthreads();
    tbuf[w][c] = g;
    __syncthreads();
    // attn MLP layer 2
    acc = sB[192 + c];
#pragma unroll
    for (int k = 0; k < 64; ++k) acc += tbuf[w][k] * sW[8192 + k * 64 + c];
    const float alpha = fmaxf(acc, 0.f);
    // softmax shift-invariance: skip segment-max (alpha >= 0, no overflow risk here)
    const float ex = expf(alpha);
    if (act) {
      const float val = ex * (v[src * 64 + c] + delta);
      atomicAdd(&num[dst * 64 + c], val);
      atomicAdd(&den[dst * 64 + c], ex);
    }
    __syncthreads();
  }
}

__global__ __launch_bounds__(256) void node_out_kernel(
    const float* __restrict__ num, const float* __restrict__ den,
    const float* __restrict__ W_out, const float* __restrict__ b_out,
    float* __restrict__ out, int N) {
  __shared__ float sW[4096];
  __shared__ float sb[64];
  __shared__ float sbuf[WAVES_PER_BLOCK][64];
  for (int i = threadIdx.x; i < 4096; i += 256) sW[i] = W_out[i];
  if (threadIdx.x < 64) sb[threadIdx.x] = b_out[threadIdx.x];
  __syncthreads();
  const int w = threadIdx.x >> 6, c = threadIdx.x & 63;
  const int npi = gridDim.x * WAVES_PER_BLOCK;
  const int iters = (N + npi - 1) / npi;
  for (int it = 0; it < iters; ++it) {
    const int n = it * npi + blockIdx.x * WAVES_PER_BLOCK + w;
    const bool act = n < N;
    float s = 0.f;
    if (act) {
      const float d = den[n * 64 + c];
      s = num[n * 64 + c] / (d + 1e-16f);
    }
    sbuf[w][c] = s;
    __syncthreads();
    float acc = sb[c];
#pragma unroll
    for (int k = 0; k < 64; ++k) acc += sbuf[w][k] * sW[k * 64 + c];
    if (act) out[n * 64 + c] = fmaxf(acc, 0.f);
    __syncthreads();
  }
}

extern "C" void kernel_launch(void* const* d_in, const int* in_sizes, int n_in,
                              void* d_out, int out_size, void* d_ws, size_t ws_size,
                              hipStream_t stream) {
  const float* x     = (const float*)d_in[0];
  const float* pos   = (const float*)d_in[1];
  const float* W_in  = (const float*)d_in[2];
  const float* b_in  = (const float*)d_in[3];
  const float* W_lin = (const float*)d_in[4];
  const float* W_src = (const float*)d_in[5];
  const float* W_dst = (const float*)d_in[6];
  const float* pW1   = (const float*)d_in[7];
  const float* pb1   = (const float*)d_in[8];
  const float* pW2   = (const float*)d_in[9];
  const float* pb2   = (const float*)d_in[10];
  const float* aW1   = (const float*)d_in[11];
  const float* ab1   = (const float*)d_in[12];
  const float* aW2   = (const float*)d_in[13];
  const float* ab2   = (const float*)d_in[14];
  const float* W_out = (const float*)d_in[15];
  const float* b_out = (const float*)d_in[16];
  const int*   eidx  = (const int*)d_in[17];

  const int N = in_sizes[0] / 64;
  const int E = in_sizes[17] / 2;

  float* ws    = (float*)d_ws;
  float* v     = ws;                       // N*64
  float* a_src = ws + (size_t)1 * N * 64;  // N*64
  float* a_dst = ws + (size_t)2 * N * 64;  // N*64
  float* num   = ws + (size_t)3 * N * 64;  // N*64
  float* den   = ws + (size_t)4 * N * 64;  // N*64

  // zero the accumulators every launch (harness poisons ws once, never re-poisons)
  hipMemsetAsync(num, 0, (size_t)2 * N * 64 * sizeof(float), stream);

  node_in_kernel<<<1024, 256, 0, stream>>>(x, W_in, b_in, W_lin, W_src, W_dst,
                                           v, a_src, a_dst, N);
  edge_kernel<<<2048, 256, 0, stream>>>(pos, v, a_src, a_dst,
                                        pW1, pb1, pW2, pb2, aW1, ab1, aW2, ab2,
                                        eidx, num, den, E);
  node_out_kernel<<<1024, 256, 0, stream>>>(num, den, W_out, b_out, (float*)d_out, N);
}